// Round 1
// baseline (285.061 us; speedup 1.0000x reference)
//
#include <hip/hip_runtime.h>
#include <hip/hip_bf16.h>

#define BB 4
#define CC 256
#define NN 16384

typedef __hip_bfloat16 bf16;
typedef __attribute__((ext_vector_type(8))) short short8;
typedef __attribute__((ext_vector_type(4))) float f32x4;

__device__ __forceinline__ float b2f(unsigned short u) {
  union { unsigned int i; float f; } x; x.i = ((unsigned int)u) << 16; return x.f;
}
__device__ __forceinline__ f32x4 mfma16(short8 a, short8 b, f32x4 c) {
  return __builtin_amdgcn_mfma_f32_16x16x32_bf16(a, b, c, 0, 0, 0);
}

// ---------------- prep: reorder/convert weights, BN constants ----------------
// W_qkv row o=3c+s -> Wq row c (s=0), Wkv row c (s=1), Wkv row 256+c (s=2)
__global__ __launch_bounds__(256) void prep_kernel(
    const float* __restrict__ Wqkv, const float* __restrict__ Wproj,
    const float* __restrict__ g, const float* __restrict__ bta,
    const float* __restrict__ mu, const float* __restrict__ var,
    bf16* __restrict__ Wq, bf16* __restrict__ Wkv, bf16* __restrict__ Wp,
    float* __restrict__ bns) {
  int i = blockIdx.x * 256 + threadIdx.x;
  if (i < 768 * 256) {
    int o = i >> 8, c8 = i & 255;
    int c = o / 3, s = o - 3 * c;
    bf16 bv = __float2bfloat16(Wqkv[i]);
    if (s == 0) Wq[c * 256 + c8] = bv;
    else if (s == 1) Wkv[c * 256 + c8] = bv;
    else Wkv[(256 + c) * 256 + c8] = bv;
  }
  int j = i - 768 * 256;
  if (j >= 0 && j < 256 * 256) Wp[j] = __float2bfloat16(Wproj[j]);
  int k = i - (768 * 256 + 256 * 256);
  if (k >= 0 && k < 256) {
    float sc = g[k] * rsqrtf(var[k] + 1e-5f);
    bns[k] = sc;
    bns[256 + k] = bta[k] - mu[k] * sc;
  }
}

// ---------------- K1: x (B,C,N) f32 -> XT (B,N,C) bf16 ----------------
__global__ __launch_bounds__(256) void xt_kernel(const float* __restrict__ X, bf16* __restrict__ XT) {
  __shared__ bf16 tile[64][65];
  int b = blockIdx.z, c0 = blockIdx.y * 64, n0 = blockIdx.x * 64;
  int t = threadIdx.x;
  int nj = t & 63, ci = t >> 6;
  const float* Xb = X + ((size_t)b * CC + c0) * NN + n0;
#pragma unroll
  for (int i = 0; i < 16; ++i)
    tile[ci + 4 * i][nj] = __float2bfloat16(Xb[(size_t)(ci + 4 * i) * NN + nj]);
  __syncthreads();
  bf16* O = XT + ((size_t)b * NN + n0) * CC + c0;
  int cj = t & 63, ni = t >> 6;
#pragma unroll
  for (int i = 0; i < 16; ++i)
    O[(size_t)(ni + 4 * i) * CC + cj] = tile[cj][ni + 4 * i];
}

// ---------------- G1a: qT (B,N,C) = relu(xT @ Wq^T) ----------------
__global__ __launch_bounds__(256) void g1a_kernel(const bf16* __restrict__ XT,
                                                  const bf16* __restrict__ Wq,
                                                  bf16* __restrict__ QT) {
  int b = blockIdx.z;
  int m0 = blockIdx.x * 128;   // n-dim
  int n0 = blockIdx.y * 128;   // c-dim
  int t = threadIdx.x, wid = t >> 6, lane = t & 63, lr = lane & 15, lk = lane >> 4;
  const bf16* A = XT + ((size_t)b * NN + m0 + wid * 32) * CC;
  const bf16* Bp = Wq + (size_t)n0 * CC;
  f32x4 acc[2][8] = {};
  for (int k0 = 0; k0 < CC; k0 += 32) {
    short8 a[2];
#pragma unroll
    for (int mt = 0; mt < 2; ++mt)
      a[mt] = *(const short8*)(A + (size_t)(mt * 16 + lr) * CC + k0 + lk * 8);
#pragma unroll
    for (int nt = 0; nt < 8; ++nt) {
      short8 bb = *(const short8*)(Bp + (size_t)(nt * 16 + lr) * CC + k0 + lk * 8);
#pragma unroll
      for (int mt = 0; mt < 2; ++mt) acc[mt][nt] = mfma16(a[mt], bb, acc[mt][nt]);
    }
  }
  bf16* O = QT + (size_t)b * NN * CC;
#pragma unroll
  for (int mt = 0; mt < 2; ++mt)
#pragma unroll
    for (int nt = 0; nt < 8; ++nt)
#pragma unroll
      for (int e = 0; e < 4; ++e) {
        int gm = m0 + wid * 32 + mt * 16 + 4 * lk + e;  // n index
        int gn = n0 + nt * 16 + lr;                     // c index
        float v = acc[mt][nt][e];
        v = v > 0.f ? v : 0.f;
        O[(size_t)gm * CC + gn] = __float2bfloat16(v);
      }
}

// ---------------- G1b: [k;v] (C,N) = Wkv @ xT^T ----------------
__global__ __launch_bounds__(256) void g1b_kernel(const bf16* __restrict__ XT,
                                                  const bf16* __restrict__ Wkv,
                                                  bf16* __restrict__ KB, bf16* __restrict__ VB) {
  int b = blockIdx.z;
  int m0 = blockIdx.x * 256;  // 0 => k(relu), 256 => v
  int n0 = blockIdx.y * 128;
  int t = threadIdx.x, wid = t >> 6, lane = t & 63, lr = lane & 15, lk = lane >> 4;
  const bf16* A = Wkv + (size_t)(m0 + wid * 64) * CC;
  const bf16* Bp = XT + ((size_t)b * NN + n0) * CC;
  f32x4 acc[4][8] = {};
  for (int k0 = 0; k0 < CC; k0 += 32) {
    short8 a[4];
#pragma unroll
    for (int mt = 0; mt < 4; ++mt)
      a[mt] = *(const short8*)(A + (size_t)(mt * 16 + lr) * CC + k0 + lk * 8);
#pragma unroll
    for (int nt = 0; nt < 8; ++nt) {
      short8 bb = *(const short8*)(Bp + (size_t)(nt * 16 + lr) * CC + k0 + lk * 8);
#pragma unroll
      for (int mt = 0; mt < 4; ++mt) acc[mt][nt] = mfma16(a[mt], bb, acc[mt][nt]);
    }
  }
  bool isK = (m0 == 0);
  bf16* Out = (isK ? KB : VB) + (size_t)b * CC * NN;
#pragma unroll
  for (int mt = 0; mt < 4; ++mt)
#pragma unroll
    for (int nt = 0; nt < 8; ++nt)
#pragma unroll
      for (int e = 0; e < 4; ++e) {
        int c = wid * 64 + mt * 16 + 4 * lk + e;
        int n = n0 + nt * 16 + lr;
        float v = acc[mt][nt][e];
        if (isK) v = v > 0.f ? v : 0.f;
        Out[(size_t)c * NN + n] = __float2bfloat16(v);
      }
}

// ---------------- G2: kvT partials (j,c) = v @ k^T, split-K 16 ----------------
__global__ __launch_bounds__(256) void g2_kernel(const bf16* __restrict__ VB,
                                                 const bf16* __restrict__ KB,
                                                 float* __restrict__ PART) {
  int b = blockIdx.z, chunk = blockIdx.y;
  int tj = (blockIdx.x & 1) * 128;
  int tc = (blockIdx.x >> 1) * 128;
  int nb = chunk * 1024;
  int t = threadIdx.x, wid = t >> 6, lane = t & 63, lr = lane & 15, lk = lane >> 4;
  const bf16* A = VB + ((size_t)b * CC + tj + wid * 32) * NN + nb;
  const bf16* Bp = KB + ((size_t)b * CC + tc) * NN + nb;
  f32x4 acc[2][8] = {};
  for (int k0 = 0; k0 < 1024; k0 += 32) {
    short8 a[2];
#pragma unroll
    for (int mt = 0; mt < 2; ++mt)
      a[mt] = *(const short8*)(A + (size_t)(mt * 16 + lr) * NN + k0 + lk * 8);
#pragma unroll
    for (int nt = 0; nt < 8; ++nt) {
      short8 bb = *(const short8*)(Bp + (size_t)(nt * 16 + lr) * NN + k0 + lk * 8);
#pragma unroll
      for (int mt = 0; mt < 2; ++mt) acc[mt][nt] = mfma16(a[mt], bb, acc[mt][nt]);
    }
  }
  float* P = PART + (((size_t)(b * 16 + chunk)) << 16);
#pragma unroll
  for (int mt = 0; mt < 2; ++mt)
#pragma unroll
    for (int nt = 0; nt < 8; ++nt)
#pragma unroll
      for (int e = 0; e < 4; ++e) {
        int j = tj + wid * 32 + mt * 16 + 4 * lk + e;
        int c = tc + nt * 16 + lr;
        P[(size_t)j * 256 + c] = acc[mt][nt][e];
      }
}

// ---------------- kvd[b,c] = sum_n k[b,c,n] ----------------
__global__ __launch_bounds__(256) void kvd_kernel(const bf16* __restrict__ KB, float* __restrict__ KVD) {
  const bf16* row = KB + (size_t)blockIdx.x * NN;
  int t = threadIdx.x, wid = t >> 6, lane = t & 63;
  float s = 0.f;
  for (int i = 0; i < 8; ++i) {
    short8 v = *(const short8*)(row + ((size_t)(i * 256 + t)) * 8);
#pragma unroll
    for (int e = 0; e < 8; ++e) s += b2f((unsigned short)v[e]);
  }
#pragma unroll
  for (int off = 32; off > 0; off >>= 1) s += __shfl_down(s, off);
  __shared__ float red[4];
  if (lane == 0) red[wid] = s;
  __syncthreads();
  if (t == 0) KVD[blockIdx.x] = red[0] + red[1] + red[2] + red[3];
}

// ---------------- reduce partials -> kvT bf16 (B,256j,256c) ----------------
__global__ __launch_bounds__(256) void kvred_kernel(const float* __restrict__ PART, bf16* __restrict__ KVT) {
  int idx = blockIdx.x * 256 + threadIdx.x;  // B*65536
  int b = idx >> 16, rem = idx & 65535;
  float s = 0.f;
#pragma unroll
  for (int ch = 0; ch < 16; ++ch) s += PART[(((size_t)(b * 16 + ch)) << 16) + rem];
  KVT[idx] = __float2bfloat16(s);
}

// ---------------- G3+G4 fused: out=q@kvT^T, normalize, y=Wp@outn^T + BN ----------------
__global__ __launch_bounds__(256) void g34_kernel(const bf16* __restrict__ QT,
                                                  const bf16* __restrict__ KVT,
                                                  const float* __restrict__ KVD,
                                                  const bf16* __restrict__ Wp,
                                                  const float* __restrict__ bns,
                                                  float* __restrict__ Y) {
  __shared__ float recip[64];
  __shared__ float s_scale[256];
  __shared__ float s_shift[256];
  __shared__ bf16 outn[64][264];  // pitch 264: 528B stride -> 2-way-free LDS banking
  int b = blockIdx.y;
  int n0 = blockIdx.x * 64;
  int t = threadIdx.x, wid = t >> 6, lane = t & 63, lr = lane & 15, lk = lane >> 4;
  s_scale[t] = bns[t];
  s_shift[t] = bns[256 + t];
  // stage 1: denominator per n-row (fp32 dot of bf16 q row with fp32 kvd)
  {
    int r = t >> 2, q4 = t & 3;
    const bf16* qrow = QT + ((size_t)b * NN + n0 + r) * CC + q4 * 64;
    const float* kd = KVD + b * 256 + q4 * 64;
    float s = 0.f;
#pragma unroll
    for (int i = 0; i < 8; ++i) {
      short8 v = *(const short8*)(qrow + i * 8);
#pragma unroll
      for (int e = 0; e < 8; ++e) s += b2f((unsigned short)v[e]) * kd[i * 8 + e];
    }
    s += __shfl_xor(s, 1);
    s += __shfl_xor(s, 2);
    if (q4 == 0) recip[r] = 1.f / (s + 1e-5f);
  }
  __syncthreads();
  // stage 2: G3 — wave handles 16 n-rows x 256 j
  {
    const bf16* A = QT + ((size_t)b * NN + n0 + wid * 16) * CC;
    const bf16* Bp = KVT + ((size_t)b << 16);
    f32x4 acc[16] = {};
    for (int k0 = 0; k0 < CC; k0 += 32) {
      short8 a = *(const short8*)(A + (size_t)lr * CC + k0 + lk * 8);
#pragma unroll
      for (int jt = 0; jt < 16; ++jt) {
        short8 bb = *(const short8*)(Bp + (size_t)(jt * 16 + lr) * CC + k0 + lk * 8);
        acc[jt] = mfma16(a, bb, acc[jt]);
      }
    }
#pragma unroll
    for (int jt = 0; jt < 16; ++jt)
#pragma unroll
      for (int e = 0; e < 4; ++e) {
        int rl = wid * 16 + 4 * lk + e;
        float v = acc[jt][e] * recip[rl];
        outn[rl][jt * 16 + lr] = __float2bfloat16(v);
      }
  }
  __syncthreads();
  // stage 3: G4 — wave handles 64 o-rows x 64 n
  {
    const bf16* A = Wp + (size_t)(wid * 64) * CC;
    f32x4 acc[4][4] = {};
    for (int k0 = 0; k0 < CC; k0 += 32) {
      short8 a[4];
#pragma unroll
      for (int mt = 0; mt < 4; ++mt)
        a[mt] = *(const short8*)(A + (size_t)(mt * 16 + lr) * CC + k0 + lk * 8);
#pragma unroll
      for (int nt = 0; nt < 4; ++nt) {
        short8 bb = *(const short8*)(&outn[nt * 16 + lr][k0 + lk * 8]);
#pragma unroll
        for (int mt = 0; mt < 4; ++mt) acc[mt][nt] = mfma16(a[mt], bb, acc[mt][nt]);
      }
    }
    float* Yb = Y + (size_t)b * CC * NN;
#pragma unroll
    for (int mt = 0; mt < 4; ++mt)
#pragma unroll
      for (int nt = 0; nt < 4; ++nt)
#pragma unroll
        for (int e = 0; e < 4; ++e) {
          int o = wid * 64 + mt * 16 + 4 * lk + e;
          int n = n0 + nt * 16 + lr;
          Yb[(size_t)o * NN + n] = acc[mt][nt][e] * s_scale[o] + s_shift[o];
        }
  }
}

extern "C" void kernel_launch(void* const* d_in, const int* in_sizes, int n_in,
                              void* d_out, int out_size, void* d_ws, size_t ws_size,
                              hipStream_t stream) {
  const float* x = (const float*)d_in[0];
  const float* Wqkv = (const float*)d_in[1];
  const float* Wproj = (const float*)d_in[2];
  const float* g = (const float*)d_in[3];
  const float* bta = (const float*)d_in[4];
  const float* mu = (const float*)d_in[5];
  const float* var = (const float*)d_in[6];
  float* Y = (float*)d_out;

  char* ws = (char*)d_ws;
  size_t off = 0;
  auto alloc = [&](size_t bytes) -> void* {
    void* p = ws + off;
    off += (bytes + 255) & ~(size_t)255;
    return p;
  };
  const size_t big = (size_t)BB * NN * CC * 2;  // 33.5 MB
  bf16* XT = (bf16*)alloc(big);
  float* PART = (float*)XT;  // overlay: XT dead before G2 writes PART
  bf16* QT = (bf16*)alloc(big);
  bf16* KB = (bf16*)alloc(big);
  bf16* VB = (bf16*)alloc(big);
  bf16* KVT = (bf16*)alloc((size_t)BB * 256 * 256 * 2);
  float* KVD = (float*)alloc((size_t)BB * 256 * 4);
  bf16* Wq = (bf16*)alloc(256 * 256 * 2);
  bf16* Wkv = (bf16*)alloc(512 * 256 * 2);
  bf16* Wp = (bf16*)alloc(256 * 256 * 2);
  float* bns = (float*)alloc(512 * 4);

  prep_kernel<<<1025, 256, 0, stream>>>(Wqkv, Wproj, g, bta, mu, var, Wq, Wkv, Wp, bns);
  xt_kernel<<<dim3(NN / 64, CC / 64, BB), 256, 0, stream>>>(x, XT);
  g1a_kernel<<<dim3(NN / 128, CC / 128, BB), 256, 0, stream>>>(XT, Wq, QT);
  g1b_kernel<<<dim3(2, NN / 128, BB), 256, 0, stream>>>(XT, Wkv, KB, VB);
  g2_kernel<<<dim3(4, 16, BB), 256, 0, stream>>>(VB, KB, PART);
  kvd_kernel<<<BB * 256, 256, 0, stream>>>(KB, KVD);
  kvred_kernel<<<BB * 256 * 256 / 256, 256, 0, stream>>>(PART, KVT);
  g34_kernel<<<dim3(NN / 64, BB), 256, 0, stream>>>(QT, KVT, KVD, Wp, bns, Y);
}

// Round 2
// 189.360 us; speedup vs baseline: 1.5054x; 1.5054x over previous
//
#include <hip/hip_runtime.h>
#include <hip/hip_bf16.h>

#define BB 4
#define CC 256
#define NN 16384

typedef __hip_bfloat16 bf16;
typedef __attribute__((ext_vector_type(8))) short short8;
typedef __attribute__((ext_vector_type(4))) float f32x4;

__device__ __forceinline__ float b2f(unsigned short u) {
  union { unsigned int i; float f; } x; x.i = ((unsigned int)u) << 16; return x.f;
}
__device__ __forceinline__ f32x4 mfma16(short8 a, short8 b, f32x4 c) {
  return __builtin_amdgcn_mfma_f32_16x16x32_bf16(a, b, c, 0, 0, 0);
}
// async global->LDS, 16B per lane; lds dst must be wave-uniform base (HW adds lane*16)
__device__ __forceinline__ void gl_lds16(const bf16* g, const bf16* s) {
  __builtin_amdgcn_global_load_lds(
      (const __attribute__((address_space(1))) unsigned int*)(g),
      (__attribute__((address_space(3))) unsigned int*)(s), 16, 0, 0);
}

// ---------------- prep: reorder/convert weights, BN constants ----------------
__global__ __launch_bounds__(256) void prep_kernel(
    const float* __restrict__ Wqkv, const float* __restrict__ Wproj,
    const float* __restrict__ g, const float* __restrict__ bta,
    const float* __restrict__ mu, const float* __restrict__ var,
    bf16* __restrict__ Wq, bf16* __restrict__ Wkv, bf16* __restrict__ Wp,
    float* __restrict__ bns) {
  int i = blockIdx.x * 256 + threadIdx.x;
  if (i < 768 * 256) {
    int o = i >> 8, c8 = i & 255;
    int c = o / 3, s = o - 3 * c;
    bf16 bv = __float2bfloat16(Wqkv[i]);
    if (s == 0) Wq[c * 256 + c8] = bv;
    else if (s == 1) Wkv[c * 256 + c8] = bv;
    else Wkv[(256 + c) * 256 + c8] = bv;
  }
  int j = i - 768 * 256;
  if (j >= 0 && j < 256 * 256) Wp[j] = __float2bfloat16(Wproj[j]);
  int k = i - (768 * 256 + 256 * 256);
  if (k >= 0 && k < 256) {
    float sc = g[k] * rsqrtf(var[k] + 1e-5f);
    bns[k] = sc;
    bns[256 + k] = bta[k] - mu[k] * sc;
  }
}

// ---------------- K1: x (B,C,N) f32 -> XT (B,N,C) bf16 ----------------
__global__ __launch_bounds__(256) void xt_kernel(const float* __restrict__ X, bf16* __restrict__ XT) {
  __shared__ bf16 tile[64][65];
  int b = blockIdx.z, c0 = blockIdx.y * 64, n0 = blockIdx.x * 64;
  int t = threadIdx.x;
  int nj = t & 63, ci = t >> 6;
  const float* Xb = X + ((size_t)b * CC + c0) * NN + n0;
#pragma unroll
  for (int i = 0; i < 16; ++i)
    tile[ci + 4 * i][nj] = __float2bfloat16(Xb[(size_t)(ci + 4 * i) * NN + nj]);
  __syncthreads();
  bf16* O = XT + ((size_t)b * NN + n0) * CC + c0;
  int cj = t & 63, ni = t >> 6;
#pragma unroll
  for (int i = 0; i < 16; ++i)
    O[(size_t)(ni + 4 * i) * CC + cj] = tile[cj][ni + 4 * i];
}

// ---------------- qkv: per 128-n tile, stage XT once, emit QT(n,c), KB(c,n), VB(c,n) ----------------
__global__ __launch_bounds__(256, 2) void qkv_kernel(
    const bf16* __restrict__ XT, const bf16* __restrict__ Wq, const bf16* __restrict__ Wkv,
    bf16* __restrict__ QT, bf16* __restrict__ KB, bf16* __restrict__ VB) {
  __shared__ bf16 xs[128 * 256];  // 64 KB, rows 512B, chunk ^= (row&7) swizzle
  int b = blockIdx.y;
  int n0 = blockIdx.x * 128;
  int t = threadIdx.x, w = t >> 6, l = t & 63, lr = l & 15, lk = l >> 4;
  const bf16* base = XT + ((size_t)b * NN + n0) * CC;
#pragma unroll
  for (int i = 0; i < 16; ++i) {
    int ldsOff = (w * 16 + i) * 1024 + l * 16;
    int r = ldsOff >> 9;
    int sc = (ldsOff >> 4) & 31;
    int cc = sc ^ (r & 7);
    gl_lds16(base + (size_t)r * CC + cc * 8, xs + ((w * 16 + i) * 512));
  }
  __syncthreads();
  const char* xb = (const char*)xs;
  // ---- phase q: out (n,c); A = xs rows n, B = Wq rows c; two c-halves to cap VGPR ----
#pragma unroll
  for (int ch = 0; ch < 2; ++ch) {
    f32x4 acc[2][8] = {};
    for (int k0 = 0; k0 < 256; k0 += 32) {
      short8 a[2];
#pragma unroll
      for (int mt = 0; mt < 2; ++mt) {
        int rr = w * 32 + mt * 16 + lr;
        a[mt] = *(const short8*)(xb + rr * 512 + ((k0 * 2 + lk * 16) ^ ((rr & 7) << 4)));
      }
#pragma unroll
      for (int nt = 0; nt < 8; ++nt) {
        short8 bb = *(const short8*)(Wq + (size_t)(ch * 128 + nt * 16 + lr) * CC + k0 + lk * 8);
#pragma unroll
        for (int mt = 0; mt < 2; ++mt) acc[mt][nt] = mfma16(a[mt], bb, acc[mt][nt]);
      }
    }
    bf16* O = QT + ((size_t)b * NN + n0 + w * 32) * CC;
#pragma unroll
    for (int mt = 0; mt < 2; ++mt)
#pragma unroll
      for (int nt = 0; nt < 8; ++nt)
#pragma unroll
        for (int e = 0; e < 4; ++e) {
          int row = mt * 16 + 4 * lk + e;
          int col = ch * 128 + nt * 16 + lr;
          float v = acc[mt][nt][e];
          O[(size_t)row * CC + col] = __float2bfloat16(v > 0.f ? v : 0.f);
        }
  }
  // ---- phases k, v: out (c,n); A = Wkv rows c, B = xs rows n ----
#pragma unroll
  for (int ph = 0; ph < 2; ++ph) {
    f32x4 acc[4][8] = {};
    for (int k0 = 0; k0 < 256; k0 += 32) {
      short8 a[4];
#pragma unroll
      for (int mt = 0; mt < 4; ++mt)
        a[mt] = *(const short8*)(Wkv + (size_t)(ph * 256 + w * 64 + mt * 16 + lr) * CC + k0 + lk * 8);
#pragma unroll
      for (int nt = 0; nt < 8; ++nt) {
        int rn = nt * 16 + lr;
        short8 bb = *(const short8*)(xb + rn * 512 + ((k0 * 2 + lk * 16) ^ ((rn & 7) << 4)));
#pragma unroll
        for (int mt = 0; mt < 4; ++mt) acc[mt][nt] = mfma16(a[mt], bb, acc[mt][nt]);
      }
    }
    bf16* Out = (ph == 0 ? KB : VB) + (size_t)b * CC * NN;
#pragma unroll
    for (int mt = 0; mt < 4; ++mt)
#pragma unroll
      for (int nt = 0; nt < 8; ++nt)
#pragma unroll
        for (int e = 0; e < 4; ++e) {
          int c = w * 64 + mt * 16 + 4 * lk + e;
          int n = nt * 16 + lr;
          float v = acc[mt][nt][e];
          if (ph == 0) v = v > 0.f ? v : 0.f;
          Out[(size_t)c * NN + n0 + n] = __float2bfloat16(v);
        }
  }
}

// ---------------- G2: PART[c][j] partials = k @ v^T, split-K 16 ----------------
__global__ __launch_bounds__(256) void g2_kernel(const bf16* __restrict__ KB,
                                                 const bf16* __restrict__ VB,
                                                 float* __restrict__ PART) {
  int b = blockIdx.z, chunk = blockIdx.y;
  int tc = (blockIdx.x & 1) * 128;   // c rows (from k)
  int tj = (blockIdx.x >> 1) * 128;  // j cols (from v)
  int nb = chunk * 1024;
  int t = threadIdx.x, w = t >> 6, lane = t & 63, lr = lane & 15, lk = lane >> 4;
  const bf16* A = KB + ((size_t)b * CC + tc + w * 32) * NN + nb;
  const bf16* Bp = VB + ((size_t)b * CC + tj) * NN + nb;
  f32x4 acc[2][8] = {};
  for (int k0 = 0; k0 < 1024; k0 += 32) {
    short8 a[2];
#pragma unroll
    for (int mt = 0; mt < 2; ++mt)
      a[mt] = *(const short8*)(A + (size_t)(mt * 16 + lr) * NN + k0 + lk * 8);
#pragma unroll
    for (int nt = 0; nt < 8; ++nt) {
      short8 bb = *(const short8*)(Bp + (size_t)(nt * 16 + lr) * NN + k0 + lk * 8);
#pragma unroll
      for (int mt = 0; mt < 2; ++mt) acc[mt][nt] = mfma16(a[mt], bb, acc[mt][nt]);
    }
  }
  float* P = PART + (((size_t)(b * 16 + chunk)) << 16);
#pragma unroll
  for (int mt = 0; mt < 2; ++mt)
#pragma unroll
    for (int nt = 0; nt < 8; ++nt)
#pragma unroll
      for (int e = 0; e < 4; ++e) {
        int c = tc + w * 32 + mt * 16 + 4 * lk + e;
        int j = tj + nt * 16 + lr;
        P[(size_t)c * 256 + j] = acc[mt][nt][e];
      }
}

// ---------------- kvd[b,c] = sum_n k[b,c,n] ----------------
__global__ __launch_bounds__(256) void kvd_kernel(const bf16* __restrict__ KB, float* __restrict__ KVD) {
  const bf16* row = KB + (size_t)blockIdx.x * NN;
  int t = threadIdx.x, wid = t >> 6, lane = t & 63;
  float s = 0.f;
  for (int i = 0; i < 8; ++i) {
    short8 v = *(const short8*)(row + ((size_t)(i * 256 + t)) * 8);
#pragma unroll
    for (int e = 0; e < 8; ++e) s += b2f((unsigned short)v[e]);
  }
#pragma unroll
  for (int off = 32; off > 0; off >>= 1) s += __shfl_down(s, off);
  __shared__ float red[4];
  if (lane == 0) red[wid] = s;
  __syncthreads();
  if (t == 0) KVD[blockIdx.x] = red[0] + red[1] + red[2] + red[3];
}

// ---------------- reduce partials -> KVJ bf16 [b][c][j] ----------------
__global__ __launch_bounds__(256) void kvred_kernel(const float* __restrict__ PART, bf16* __restrict__ KVJ) {
  int idx = blockIdx.x * 256 + threadIdx.x;
  int b = idx >> 16, rem = idx & 65535;
  float s = 0.f;
#pragma unroll
  for (int ch = 0; ch < 16; ++ch) s += PART[(((size_t)(b * 16 + ch)) << 16) + rem];
  KVJ[idx] = __float2bfloat16(s);
}

// ---------------- mker: M[o][c] = scale[o] * sum_j Wp[o,j] * KVJ[c,j] ----------------
__global__ __launch_bounds__(256) void mker_kernel(const bf16* __restrict__ Wp,
                                                   const bf16* __restrict__ KVJ,
                                                   const float* __restrict__ bns,
                                                   bf16* __restrict__ Mb) {
  int b = blockIdx.z;
  int o0 = blockIdx.x * 128, c0 = blockIdx.y * 128;
  int t = threadIdx.x, w = t >> 6, lane = t & 63, lr = lane & 15, lk = lane >> 4;
  const bf16* A = Wp + (size_t)(o0 + w * 32) * 256;
  const bf16* Bp = KVJ + ((size_t)b << 16) + (size_t)c0 * 256;
  f32x4 acc[2][8] = {};
  for (int k0 = 0; k0 < 256; k0 += 32) {
    short8 a[2];
#pragma unroll
    for (int mt = 0; mt < 2; ++mt)
      a[mt] = *(const short8*)(A + (size_t)(mt * 16 + lr) * 256 + k0 + lk * 8);
#pragma unroll
    for (int nt = 0; nt < 8; ++nt) {
      short8 bb = *(const short8*)(Bp + (size_t)(nt * 16 + lr) * 256 + k0 + lk * 8);
#pragma unroll
      for (int mt = 0; mt < 2; ++mt) acc[mt][nt] = mfma16(a[mt], bb, acc[mt][nt]);
    }
  }
#pragma unroll
  for (int mt = 0; mt < 2; ++mt)
#pragma unroll
    for (int nt = 0; nt < 8; ++nt)
#pragma unroll
      for (int e = 0; e < 4; ++e) {
        int o = o0 + w * 32 + mt * 16 + 4 * lk + e;
        int c = c0 + nt * 16 + lr;
        Mb[((size_t)b << 16) + (size_t)o * 256 + c] = __float2bfloat16(acc[mt][nt][e] * bns[o]);
      }
}

// ---------------- g5: y[o,n] = (sum_c M[o,c] q[n,c]) * recip[n] + shift[o] ----------------
__global__ __launch_bounds__(256, 2) void g5_kernel(const bf16* __restrict__ QT,
                                                    const bf16* __restrict__ Mb,
                                                    const float* __restrict__ KVD,
                                                    const float* __restrict__ bns,
                                                    float* __restrict__ Y) {
  __shared__ bf16 qs[128 * 128];   // 32 KB, rows 256B, chunk ^= (row&7)
  __shared__ float recip_s[128];
  __shared__ float shift_s[256];
  int b = blockIdx.y;
  int n0 = blockIdx.x * 128;
  int t = threadIdx.x, w = t >> 6, l = t & 63, lr = l & 15, lk = l >> 4;
  shift_s[t] = bns[256 + t];
  const bf16* qbase = QT + ((size_t)b * NN + n0) * CC;
  const bf16* Ab = Mb + ((size_t)b << 16) + (size_t)(w * 64) * 256;
  const float* kd = KVD + b * 256;
  const char* qb = (const char*)qs;
  float den = 0.f;
  f32x4 acc[4][8] = {};
#pragma unroll
  for (int h = 0; h < 2; ++h) {
    if (h) __syncthreads();
#pragma unroll
    for (int i = 0; i < 8; ++i) {
      int ldsOff = (w * 8 + i) * 1024 + l * 16;
      int r = ldsOff >> 8;
      int sc = (ldsOff >> 4) & 15;
      int cc = sc ^ (r & 7);
      gl_lds16(qbase + (size_t)r * CC + h * 128 + cc * 8, qs + ((w * 8 + i) * 512));
    }
    __syncthreads();
    // denominator partial from staged tile
    {
      int row = t >> 1, seg = t & 1;
      float s = 0.f;
#pragma unroll
      for (int jj = 0; jj < 8; ++jj) {
        int chunk = seg * 8 + jj;
        short8 v = *(const short8*)(qb + row * 256 + ((chunk * 16) ^ ((row & 7) << 4)));
        const float* kp = kd + h * 128 + chunk * 8;
#pragma unroll
        for (int e = 0; e < 8; ++e) s += b2f((unsigned short)v[e]) * kp[e];
      }
      den += s;
    }
    // GEMM over this K-half
    for (int kk = 0; kk < 128; kk += 32) {
      short8 a[4];
#pragma unroll
      for (int mt = 0; mt < 4; ++mt)
        a[mt] = *(const short8*)(Ab + (size_t)(mt * 16 + lr) * 256 + h * 128 + kk + lk * 8);
#pragma unroll
      for (int nt = 0; nt < 8; ++nt) {
        int rn = nt * 16 + lr;
        short8 bb = *(const short8*)(qb + rn * 256 + ((kk * 2 + lk * 16) ^ ((rn & 7) << 4)));
#pragma unroll
        for (int mt = 0; mt < 4; ++mt) acc[mt][nt] = mfma16(a[mt], bb, acc[mt][nt]);
      }
    }
  }
  den += __shfl_xor(den, 1);
  if ((t & 1) == 0) recip_s[t >> 1] = 1.f / (den + 1e-5f);
  __syncthreads();
  float* Yb = Y + (size_t)b * CC * NN;
#pragma unroll
  for (int mt = 0; mt < 4; ++mt)
#pragma unroll
    for (int nt = 0; nt < 8; ++nt)
#pragma unroll
      for (int e = 0; e < 4; ++e) {
        int o = w * 64 + mt * 16 + 4 * lk + e;
        int n = nt * 16 + lr;
        Yb[(size_t)o * NN + n0 + n] = acc[mt][nt][e] * recip_s[n] + shift_s[o];
      }
}

extern "C" void kernel_launch(void* const* d_in, const int* in_sizes, int n_in,
                              void* d_out, int out_size, void* d_ws, size_t ws_size,
                              hipStream_t stream) {
  const float* x = (const float*)d_in[0];
  const float* Wqkv = (const float*)d_in[1];
  const float* Wproj = (const float*)d_in[2];
  const float* g = (const float*)d_in[3];
  const float* bta = (const float*)d_in[4];
  const float* mu = (const float*)d_in[5];
  const float* var = (const float*)d_in[6];
  float* Y = (float*)d_out;

  char* ws = (char*)d_ws;
  size_t off = 0;
  auto alloc = [&](size_t bytes) -> void* {
    void* p = ws + off;
    off += (bytes + 255) & ~(size_t)255;
    return p;
  };
  const size_t big = (size_t)BB * NN * CC * 2;  // 33.5 MB
  bf16* XT = (bf16*)alloc(big);
  float* PART = (float*)XT;  // overlay: XT dead before g2 writes PART
  bf16* QT = (bf16*)alloc(big);
  bf16* KB = (bf16*)alloc(big);
  bf16* VB = (bf16*)alloc(big);
  bf16* KVJ = (bf16*)alloc((size_t)BB * 256 * 256 * 2);
  bf16* Mbuf = (bf16*)alloc((size_t)BB * 256 * 256 * 2);
  float* KVD = (float*)alloc((size_t)BB * 256 * 4);
  bf16* Wq = (bf16*)alloc(256 * 256 * 2);
  bf16* Wkv = (bf16*)alloc(512 * 256 * 2);
  bf16* Wp = (bf16*)alloc(256 * 256 * 2);
  float* bns = (float*)alloc(512 * 4);

  prep_kernel<<<1025, 256, 0, stream>>>(Wqkv, Wproj, g, bta, mu, var, Wq, Wkv, Wp, bns);
  xt_kernel<<<dim3(NN / 64, CC / 64, BB), 256, 0, stream>>>(x, XT);
  qkv_kernel<<<dim3(NN / 128, BB), 256, 0, stream>>>(XT, Wq, Wkv, QT, KB, VB);
  g2_kernel<<<dim3(4, 16, BB), 256, 0, stream>>>(KB, VB, PART);
  kvd_kernel<<<BB * 256, 256, 0, stream>>>(KB, KVD);
  kvred_kernel<<<BB * 256 * 256 / 256, 256, 0, stream>>>(PART, KVJ);
  mker_kernel<<<dim3(2, 2, BB), 256, 0, stream>>>(Wp, KVJ, bns, Mbuf);
  g5_kernel<<<dim3(NN / 128, BB), 256, 0, stream>>>(QT, Mbuf, KVD, bns, Y);
}